// Round 12
// baseline (248.844 us; speedup 1.0000x reference)
//
#include <hip/hip_runtime.h>
#include <hip/hip_bf16.h>

typedef unsigned short u16;
typedef unsigned int u32;

#define TT 192
#define BB 2
#define HH 8
#define DD 64
#define CC 512
#define MM (BB*TT)   // 384

// ws layout (u16 elements): Q,K0,K1,V0,V1 each [bh][t][d], then ATT [m][c],
// then grid-barrier cells (u32 flags[1024] + go[2]).
#define TSZ   ((size_t)MM * CC)
#define OFF_ATT (5 * TSZ)
#define OFF_BAR (6 * TSZ)              // u16 offset; cast to u32*

#define MAXBLK 1024
#define TAG1 0x51A7F001u
#define TAG2 0x51A7F002u

typedef short bf16x8 __attribute__((ext_vector_type(8)));
typedef float f32x4  __attribute__((ext_vector_type(4)));

union FragU { uint4 u; bf16x8 b; };

__device__ __forceinline__ float bf2f(u16 u) {
    return __uint_as_float(((u32)u) << 16);
}
__device__ __forceinline__ u16 f2bf(float f) {
    u32 u = __float_as_uint(f);
    u32 r = u + 0x7FFFu + ((u >> 16) & 1u);   // RNE
    return (u16)(r >> 16);
}
// pack hi16(a),hi16(b) -> one u32 (truncation round; bias cancels in P/Z)
__device__ __forceinline__ u32 trunc_pk(u32 b_hi, u32 a_lo) {
    return __builtin_amdgcn_perm(b_hi, a_lo, 0x07060302u);
}

// dtype detect: 1 load + ballot. bf16 data => low u16 exponent near 127.
__device__ __forceinline__ u32 detect_bf16_fast(const u32* __restrict__ x) {
    const int lane = threadIdx.x & 63;
    u32 v = x[lane & 31];
    u32 e = (v >> 7) & 0xFF;
    unsigned long long m = __ballot(e >= 113 && e <= 133);
    return (__popcll(m) >= 32) ? 1u : 0u;
}

// dtype-aware 16-element load (two uint4 of packed bf16)
__device__ __forceinline__ void ld16(const void* __restrict__ base, size_t off, u32 fl,
                                     uint4& lo, uint4& hi) {
    if (fl) {
        const uint4* p = (const uint4*)((const u16*)base + off);
        lo = p[0]; hi = p[1];
    } else {
        const float* s = (const float*)base + off;
        float4 f0 = *(const float4*)(s);
        float4 f1 = *(const float4*)(s + 4);
        float4 f2 = *(const float4*)(s + 8);
        float4 f3 = *(const float4*)(s + 12);
        lo = make_uint4((u32)f2bf(f0.x) | ((u32)f2bf(f0.y) << 16),
                        (u32)f2bf(f0.z) | ((u32)f2bf(f0.w) << 16),
                        (u32)f2bf(f1.x) | ((u32)f2bf(f1.y) << 16),
                        (u32)f2bf(f1.z) | ((u32)f2bf(f1.w) << 16));
        hi = make_uint4((u32)f2bf(f2.x) | ((u32)f2bf(f2.y) << 16),
                        (u32)f2bf(f2.z) | ((u32)f2bf(f2.w) << 16),
                        (u32)f2bf(f3.x) | ((u32)f2bf(f3.y) << 16),
                        (u32)f2bf(f3.z) | ((u32)f2bf(f3.w) << 16));
    }
}

// ---------------------------------------------------------------------------
// Device-scope grid barrier. Population = gridDim.x, sized by the host from
// hipOccupancyMaxActiveBlocksPerMultiprocessor (co-residency MEASURED).
// flags/go cells live in d_ws (re-poisoned 0xAA before every timed launch,
// so TAG values are always fresh).
// ---------------------------------------------------------------------------
__device__ __forceinline__ void grid_barrier(u32* flags, u32* goc, u32 tag) {
    const int nblk = gridDim.x;
    const int blk = blockIdx.x;
    __syncthreads();
    if (threadIdx.x == 0) {
        __threadfence();
        __hip_atomic_store(&flags[blk], tag, __ATOMIC_RELEASE, __HIP_MEMORY_SCOPE_AGENT);
    }
    if (blk == 0) {
        for (int i = threadIdx.x; i < nblk; i += 256) {
            while (__hip_atomic_load(&flags[i], __ATOMIC_ACQUIRE, __HIP_MEMORY_SCOPE_AGENT) != tag)
                __builtin_amdgcn_s_sleep(8);
        }
        __syncthreads();
        if (threadIdx.x == 0)
            __hip_atomic_store(goc, tag, __ATOMIC_RELEASE, __HIP_MEMORY_SCOPE_AGENT);
    }
    if (threadIdx.x == 0) {
        while (__hip_atomic_load(goc, __ATOMIC_ACQUIRE, __HIP_MEMORY_SCOPE_AGENT) != tag)
            __builtin_amdgcn_s_sleep(8);
        __threadfence();
    }
    __syncthreads();
}

// ---------------------------------------------------------------------------
// LDS-staged MFMA projection tile. __noinline__: keeps its register frame
// separate from attn's so the fused kernel's VGPR = max(phases), not union
// (r11: inlined union = 144 VGPR -> 3 waves/SIMD -> fused ran 2.5x slow).
// Uses 9216 u16 (18432 B) of smem.
// ---------------------------------------------------------------------------
__device__ __noinline__ void proj_tile(const void* __restrict__ A, u32 aFl,
                                       const void* __restrict__ W,
                                       const void* __restrict__ bias, u32 wFl,
                                       void* __restrict__ out, int headperm, u32 outFl,
                                       int mb, int nb, u16* __restrict__ smem) {
    u16 (*As)[72] = (u16(*)[72])smem;
    u16 (*Ws)[72] = (u16(*)[72])(smem + 4608);
    const int tid = threadIdx.x;
    const int w = tid >> 6, lane = tid & 63;
    const int quad = lane >> 4, li = lane & 15;

    const int r = tid >> 2;            // 0..63: tile row this thread stages
    const int c = (tid & 3) * 16;      // 0,16,32,48: k-chunk (u16 units)

    const size_t abase = (size_t)(mb + r) * CC + c;
    const size_t wbase = (size_t)(nb + r) * CC + c;

    f32x4 acc[4];
#pragma unroll
    for (int ct = 0; ct < 4; ct++) acc[ct] = (f32x4){0.f, 0.f, 0.f, 0.f};

    uint4 a0, a1, w0, w1;
    ld16(A, abase, aFl, a0, a1);
    ld16(W, wbase, wFl, w0, w1);

#pragma unroll
    for (int step = 0; step < 8; step++) {
        __syncthreads();   // previous step's LDS reads done (also first-entry safe)
        *(uint4*)&As[r][c] = a0; *(uint4*)&As[r][c + 8] = a1;
        *(uint4*)&Ws[r][c] = w0; *(uint4*)&Ws[r][c + 8] = w1;
        __syncthreads();
        if (step < 7) {
            const int kb = (step + 1) * 64;
            ld16(A, abase + kb, aFl, a0, a1);
            ld16(W, wbase + kb, wFl, w0, w1);
        }
#pragma unroll
        for (int kk = 0; kk < 2; kk++) {
            FragU af; af.u = *(const uint4*)&As[w * 16 + li][kk * 32 + quad * 8];
#pragma unroll
            for (int ct = 0; ct < 4; ct++) {
                FragU wf; wf.u = *(const uint4*)&Ws[ct * 16 + li][kk * 32 + quad * 8];
                acc[ct] = __builtin_amdgcn_mfma_f32_16x16x32_bf16(af.b, wf.b, acc[ct], 0, 0, 0);
            }
        }
    }
    __syncthreads();   // last step's LDS reads done before caller reuses smem

#pragma unroll
    for (int ct = 0; ct < 4; ct++) {
        const int n = nb + ct * 16 + li;
        const float bv = wFl ? bf2f(((const u16*)bias)[n]) : ((const float*)bias)[n];
#pragma unroll
        for (int rr = 0; rr < 4; rr++) {
            const int m = mb + w * 16 + quad * 4 + rr;
            const float v = acc[ct][rr] + bv;
            if (headperm) {
                const int b = (m >= TT) ? 1 : 0;
                const int tloc = m - b * TT;
                ((u16*)out)[((size_t)(b * HH + (n >> 6)) * TT + tloc) * DD + (n & 63)] = f2bf(v);
            } else {
                if (outFl) ((u16*)out)[(size_t)m * CC + n] = f2bf(v);
                else       ((float*)out)[(size_t)m * CC + n] = v;
            }
        }
    }
}

// ---------------------------------------------------------------------------
// Attention group: v1^T staged once, then kcount consecutive k's.
// Core = r9 attn (best measured). __noinline__ per above.
// LDS use: v1t [64][200] @0 | P [192][40] @12800 (osum overlays P).
// ---------------------------------------------------------------------------
#define LP_P  12800
#define LP_OS 12800

__device__ __noinline__ void attn_group(u16* __restrict__ ws16, int bh, int kbase,
                                        int kcount, u16* __restrict__ smem) {
    const int tid = threadIdx.x;
    const int w = tid >> 6, lane = tid & 63;
    const int quad = lane >> 4, li = lane & 15;

    const u16* k0g = ws16 + TSZ     + (size_t)bh * TT * DD;
    const u16* k1g = ws16 + 2 * TSZ + (size_t)bh * TT * DD;
    const u16* v0g = ws16 + 3 * TSZ + (size_t)bh * TT * DD;
    const u16* v1g = ws16 + 4 * TSZ + (size_t)bh * TT * DD;

    // ---- stage v1^T (stride 200, swz (m>>3)^(d>>3); stores 2-way max) ----
#pragma unroll
    for (int it = 0; it < 6; it++) {
        const int flat = (it * 256 + tid) * 8;
        const int row = flat >> 6, c0 = flat & 63;   // row=m, c0=d base
        uint4 b = *(const uint4*)(v1g + flat);
        u16 vb[8]; *(uint4*)vb = b;
        const int swz = (((row >> 3) ^ (c0 >> 3)) << 3) | (row & 7);
#pragma unroll
        for (int j = 0; j < 8; j++)
            smem[(c0 + j) * 200 + swz] = vb[j];
    }
    __syncthreads();   // v1t staged

    FragU ones;
    ones.u = make_uint4(0x3F803F80u, 0x3F803F80u, 0x3F803F80u, 0x3F803F80u);

    for (int ki = 0; ki < kcount; ki++) {
        const int k = kbase + ki;
        const u16* qg = ws16 + ((size_t)bh * TT + k) * DD;

        // ---- afr: a[l,d] = bf16_trunc(scl*q[d]*k0[l,d]), scl=0.125*log2e ----
        FragU afr[3][2];
#pragma unroll
        for (int kk = 0; kk < 2; kk++) {
            uint4 qu = *(const uint4*)(qg + kk * 32 + quad * 8);
            u16 qv[8]; *(uint4*)qv = qu;
            float qf[8];
#pragma unroll
            for (int j = 0; j < 8; j++) qf[j] = bf2f(qv[j]) * 0.18033688f;
#pragma unroll
            for (int rt = 0; rt < 3; rt++) {
                uint4 ku = *(const uint4*)(k0g + (size_t)(w * 48 + rt * 16 + li) * DD + kk * 32 + quad * 8);
                u16 kv[8]; *(uint4*)kv = ku;
                u32 pk[4];
#pragma unroll
                for (int p = 0; p < 4; p++) {
                    u32 lo = __float_as_uint(qf[2 * p] * bf2f(kv[2 * p]));
                    u32 hi = __float_as_uint(qf[2 * p + 1] * bf2f(kv[2 * p + 1]));
                    pk[p] = trunc_pk(hi, lo);
                }
                afr[rt][kk].u = make_uint4(pk[0], pk[1], pk[2], pk[3]);
            }
        }

        f32x4 Wacc[3][4], Zacc[3];
#pragma unroll
        for (int rt = 0; rt < 3; rt++) {
            Zacc[rt] = (f32x4){0.f, 0.f, 0.f, 0.f};
#pragma unroll
            for (int cd = 0; cd < 4; cd++) Wacc[rt][cd] = (f32x4){0.f, 0.f, 0.f, 0.f};
        }

        // ---- m-tile loop (6 x 32), barrier-free (P rows wave-private) ----
        for (int mt = 0; mt < 6; mt++) {
#pragma unroll
            for (int ct = 0; ct < 2; ct++) {
                const u16* krow = k1g + (size_t)(mt * 32 + ct * 16 + li) * DD + quad * 8;
                FragU kf0, kf1;
                kf0.u = *(const uint4*)(krow);
                kf1.u = *(const uint4*)(krow + 32);
#pragma unroll
                for (int rt = 0; rt < 3; rt++) {
                    f32x4 acc = (f32x4){0.f, 0.f, 0.f, 0.f};
                    acc = __builtin_amdgcn_mfma_f32_16x16x32_bf16(kf0.b, afr[rt][0].b, acc, 0, 0, 0);
                    acc = __builtin_amdgcn_mfma_f32_16x16x32_bf16(kf1.b, afr[rt][1].b, acc, 0, 0, 0);
                    u32 lo = trunc_pk(__float_as_uint(exp2f(acc[1])), __float_as_uint(exp2f(acc[0])));
                    u32 hi = trunc_pk(__float_as_uint(exp2f(acc[3])), __float_as_uint(exp2f(acc[2])));
                    const int l = w * 48 + rt * 16 + li;
                    *(uint2*)(smem + LP_P + l * 40 + ct * 16 + quad * 4) = make_uint2(lo, hi);
                }
            }
            FragU a2[3], b2[4];
#pragma unroll
            for (int rt = 0; rt < 3; rt++)
                a2[rt].u = *(const uint4*)(smem + LP_P + (w * 48 + rt * 16 + li) * 40 + quad * 8);
#pragma unroll
            for (int cd = 0; cd < 4; cd++) {
                const int d = cd * 16 + li;
                b2[cd].u = *(const uint4*)(smem + d * 200 + (((mt * 4 + quad) ^ (d >> 3)) << 3));
            }
#pragma unroll
            for (int rt = 0; rt < 3; rt++) {
                Zacc[rt] = __builtin_amdgcn_mfma_f32_16x16x32_bf16(a2[rt].b, ones.b, Zacc[rt], 0, 0, 0);
#pragma unroll
                for (int cd = 0; cd < 4; cd++)
                    Wacc[rt][cd] = __builtin_amdgcn_mfma_f32_16x16x32_bf16(a2[rt].b, b2[cd].b, Wacc[rt][cd], 0, 0, 0);
            }
        }

        __syncthreads();   // all waves done with this k's P (osum overlays P rows 0..12)

        // ---- epilogue: v0 from global, per-rt to cap live VGPRs ----
        float op[4] = {0.f, 0.f, 0.f, 0.f};
#pragma unroll
        for (int rt = 0; rt < 3; rt++) {
            float v0v[4][4];
#pragma unroll
            for (int r = 0; r < 4; r++) {
                const int l = w * 48 + rt * 16 + quad * 4 + r;
#pragma unroll
                for (int cd = 0; cd < 4; cd++)
                    v0v[r][cd] = bf2f(v0g[(size_t)l * DD + cd * 16 + li]);
            }
#pragma unroll
            for (int r = 0; r < 4; r++) {
                const float iv = 1.f / Zacc[rt][r];
#pragma unroll
                for (int cd = 0; cd < 4; cd++)
                    op[cd] = fmaf(v0v[r][cd] * iv, Wacc[rt][cd][r], op[cd]);
            }
        }
#pragma unroll
        for (int cd = 0; cd < 4; cd++) {
            op[cd] += __shfl_xor(op[cd], 16);
            op[cd] += __shfl_xor(op[cd], 32);
        }
        float* osum = (float*)(smem + LP_OS);
        if (quad == 0) {
#pragma unroll
            for (int cd = 0; cd < 4; cd++) osum[w * 64 + cd * 16 + li] = op[cd];
        }
        __syncthreads();
        if (tid < DD) {
            const float o = osum[tid] + osum[64 + tid] + osum[128 + tid] + osum[192 + tid];
            const int b = bh >> 3, h = bh & 7;
            u16* ATT = ws16 + OFF_ATT;
            ATT[((size_t)(b * TT + k)) * CC + h * DD + tid] = f2bf(o);
        }
        // Race audit (r11): osum readers = wave 0; overlapping next-P writes
        // are wave 0's own rows (program order); v1t region disjoint. Safe.
    }
}

// ---------------------------------------------------------------------------
// Fused single-dispatch kernel. Strided task loops work for any grid size;
// host sizes grid to measured co-residency (<= 4 blocks/CU: LDS 40960*4 =
// exactly 160 KiB).
//   phase 1: 240 QKV projection tiles | barrier |
//   phase 2: 1024 attn groups (bh, 3 consecutive k; v1t amortized) | barrier |
//   phase 3: 48 output-projection tiles
// ---------------------------------------------------------------------------
__global__ __launch_bounds__(256) void fused_kernel(
    const void* __restrict__ x,
    const void* __restrict__ Wq,  const void* __restrict__ bq,
    const void* __restrict__ Wk0, const void* __restrict__ bk0,
    const void* __restrict__ Wk1, const void* __restrict__ bk1,
    const void* __restrict__ Wv0, const void* __restrict__ bv0,
    const void* __restrict__ Wv1, const void* __restrict__ bv1,
    const void* __restrict__ Wo,  const void* __restrict__ bo,
    void* __restrict__ out, u16* __restrict__ ws16) {
    __shared__ __align__(16) u16 smem[20480];   // 40960 B
    const u32 fl = detect_bf16_fast((const u32*)x);
    u32* flags = (u32*)(ws16 + OFF_BAR);
    u32* goc   = flags + MAXBLK;

    for (int t = blockIdx.x; t < 240; t += gridDim.x) {
        const int z = t / 48, rem = t % 48;
        const void* W; const void* bi;
        switch (z) {
            case 0:  W = Wq;  bi = bq;  break;
            case 1:  W = Wk0; bi = bk0; break;
            case 2:  W = Wk1; bi = bk1; break;
            case 3:  W = Wv0; bi = bv0; break;
            default: W = Wv1; bi = bv1; break;
        }
        proj_tile(x, fl, W, bi, fl, (void*)(ws16 + (size_t)z * TSZ), 1, 1u,
                  (rem >> 3) * 64, (rem & 7) * 64, smem);
    }

    grid_barrier(flags, &goc[0], TAG1);

    for (int g = blockIdx.x; g < 1024; g += gridDim.x)
        attn_group(ws16, g >> 6, (g & 63) * 3, 3, smem);

    grid_barrier(flags, &goc[1], TAG2);

    for (int t = blockIdx.x; t < 48; t += gridDim.x)
        proj_tile(ws16 + OFF_ATT, 1u, Wo, bo, fl, out, 0, fl,
                  (t >> 3) * 64, (t & 7) * 64, smem);
}

// ---------------------------------------------------------------------------
// Fallback path: r9's three dispatches (known-good, 165us).
// ---------------------------------------------------------------------------
__global__ __launch_bounds__(256) void proj5_kernel(
    const void* __restrict__ x,
    const void* __restrict__ Wq,  const void* __restrict__ bq,
    const void* __restrict__ Wk0, const void* __restrict__ bk0,
    const void* __restrict__ Wk1, const void* __restrict__ bk1,
    const void* __restrict__ Wv0, const void* __restrict__ bv0,
    const void* __restrict__ Wv1, const void* __restrict__ bv1,
    u16* __restrict__ ws16) {
    __shared__ __align__(16) u16 smem[9216];
    const u32 fl = detect_bf16_fast((const u32*)x);
    const int z = blockIdx.z;
    const void* W; const void* bi;
    switch (z) {
        case 0:  W = Wq;  bi = bq;  break;
        case 1:  W = Wk0; bi = bk0; break;
        case 2:  W = Wk1; bi = bk1; break;
        case 3:  W = Wv0; bi = bv0; break;
        default: W = Wv1; bi = bv1; break;
    }
    proj_tile(x, fl, W, bi, fl, (void*)(ws16 + (size_t)z * TSZ), 1, 1u,
              blockIdx.y * 64, blockIdx.x * 64, smem);
}

__global__ __launch_bounds__(256) void attn_kernel(u16* __restrict__ ws16) {
    __shared__ __align__(16) u16 smem[20480];
    attn_group(ws16, blockIdx.y, blockIdx.x, 1, smem);
}

__global__ __launch_bounds__(256) void projo_kernel(const u16* __restrict__ ws16,
                                                    const void* __restrict__ Wo,
                                                    const void* __restrict__ bo,
                                                    void* __restrict__ out,
                                                    const void* __restrict__ xorig) {
    __shared__ __align__(16) u16 smem[9216];
    const u32 fl = detect_bf16_fast((const u32*)xorig);
    proj_tile(ws16 + OFF_ATT, 1u, Wo, bo, fl, out, 0, fl,
              blockIdx.y * 64, blockIdx.x * 64, smem);
}

extern "C" void kernel_launch(void* const* d_in, const int* in_sizes, int n_in,
                              void* d_out, int out_size, void* d_ws, size_t ws_size,
                              hipStream_t stream) {
    u16* ws16 = (u16*)d_ws;

    // Measure co-residency for the compiled fused kernel (host introspection;
    // graph-capture-safe, deterministic every call).
    int maxb = 0;
    hipError_t e = hipOccupancyMaxActiveBlocksPerMultiprocessor(&maxb, fused_kernel, 256, 0);
    int nblk = 0;
    if (e == hipSuccess && maxb >= 1) nblk = ((maxb < 4) ? maxb : 4) * 256;

    if (nblk >= 256) {
        fused_kernel<<<nblk, 256, 0, stream>>>(
            d_in[0], d_in[1], d_in[2], d_in[3], d_in[4], d_in[5], d_in[6],
            d_in[7], d_in[8], d_in[9], d_in[10], d_in[11], d_in[12],
            d_out, ws16);
    } else {
        dim3 gp(CC / 64, MM / 64, 5);
        proj5_kernel<<<gp, 256, 0, stream>>>(
            d_in[0], d_in[1], d_in[2], d_in[3], d_in[4], d_in[5], d_in[6],
            d_in[7], d_in[8], d_in[9], d_in[10], ws16);
        dim3 ga(TT, BB * HH);
        attn_kernel<<<ga, 256, 0, stream>>>(ws16);
        dim3 go(CC / 64, MM / 64, 1);
        projo_kernel<<<go, 256, 0, stream>>>(ws16, d_in[11], d_in[12], d_out, d_in[0]);
    }
}

// Round 13
// 174.252 us; speedup vs baseline: 1.4281x; 1.4281x over previous
//
#include <hip/hip_runtime.h>
#include <hip/hip_bf16.h>

typedef unsigned short u16;
typedef unsigned int u32;

#define TT 192
#define BB 2
#define HH 8
#define DD 64
#define CC 512
#define MM (BB*TT)   // 384

// ws layout (u16 elements): Q,K0,K1,V0,V1 each [bh][t][d], then ATT [m][c]
#define TSZ   ((size_t)MM * CC)
#define OFF_ATT (5 * TSZ)

typedef short bf16x8 __attribute__((ext_vector_type(8)));
typedef float f32x4  __attribute__((ext_vector_type(4)));

union FragU { uint4 u; bf16x8 b; };

// Raw HW transcendentals: without -ffast-math, exp2f/1.f/x lower to guarded
// multi-instruction libm sequences; these are single v_exp_f32 / v_rcp_f32.
// ~1ulp accuracy -- irrelevant vs the 2%-of-max bf16 threshold.
#if __has_builtin(__builtin_amdgcn_exp2f)
#define EXP2F(x) __builtin_amdgcn_exp2f(x)
#else
#define EXP2F(x) exp2f(x)
#endif
#if __has_builtin(__builtin_amdgcn_rcpf)
#define RCPF(x) __builtin_amdgcn_rcpf(x)
#else
#define RCPF(x) (1.f / (x))
#endif

__device__ __forceinline__ float bf2f(u16 u) {
    return __uint_as_float(((u32)u) << 16);
}
__device__ __forceinline__ u16 f2bf(float f) {
    u32 u = __float_as_uint(f);
    u32 r = u + 0x7FFFu + ((u >> 16) & 1u);   // RNE
    return (u16)(r >> 16);
}
// pack hi16(a),hi16(b) -> one u32 (truncation round; bias cancels in P/Z)
__device__ __forceinline__ u32 trunc_pk(u32 b_hi, u32 a_lo) {
    return __builtin_amdgcn_perm(b_hi, a_lo, 0x07060302u);
}

// dtype detect: 1 load + ballot. bf16 data => low u16 exponent near 127.
__device__ __forceinline__ u32 detect_bf16_fast(const u32* __restrict__ x) {
    const int lane = threadIdx.x & 63;
    u32 v = x[lane & 31];
    u32 e = (v >> 7) & 0xFF;
    unsigned long long m = __ballot(e >= 113 && e <= 133);
    return (__popcll(m) >= 32) ? 1u : 0u;
}

// dtype-aware 16-element load (two uint4 of packed bf16)
__device__ __forceinline__ void ld16(const void* __restrict__ base, size_t off, u32 fl,
                                     uint4& lo, uint4& hi) {
    if (fl) {
        const uint4* p = (const uint4*)((const u16*)base + off);
        lo = p[0]; hi = p[1];
    } else {
        const float* s = (const float*)base + off;
        float4 f0 = *(const float4*)(s);
        float4 f1 = *(const float4*)(s + 4);
        float4 f2 = *(const float4*)(s + 8);
        float4 f3 = *(const float4*)(s + 12);
        lo = make_uint4((u32)f2bf(f0.x) | ((u32)f2bf(f0.y) << 16),
                        (u32)f2bf(f0.z) | ((u32)f2bf(f0.w) << 16),
                        (u32)f2bf(f1.x) | ((u32)f2bf(f1.y) << 16),
                        (u32)f2bf(f1.z) | ((u32)f2bf(f1.w) << 16));
        hi = make_uint4((u32)f2bf(f2.x) | ((u32)f2bf(f2.y) << 16),
                        (u32)f2bf(f2.z) | ((u32)f2bf(f2.w) << 16),
                        (u32)f2bf(f3.x) | ((u32)f2bf(f3.y) << 16),
                        (u32)f2bf(f3.z) | ((u32)f2bf(f3.w) << 16));
    }
}

// ---------------------------------------------------------------------------
// LDS-staged MFMA projection GEMM (r9-verified): out = A @ W^T + bias.
// 64x64 tile, 4 waves, BK=64, coalesced 128B staging, stride-72 LDS,
// register prefetch of step k+1.
// ---------------------------------------------------------------------------
__device__ __forceinline__ void proj_lds(const void* __restrict__ A, u32 aFl,
                                         const void* __restrict__ W,
                                         const void* __restrict__ bias, u32 wFl,
                                         void* __restrict__ out, int headperm, u32 outFl) {
    __shared__ __align__(16) u16 As[64][72];
    __shared__ __align__(16) u16 Ws[64][72];
    const int tid = threadIdx.x;
    const int w = tid >> 6, lane = tid & 63;
    const int quad = lane >> 4, li = lane & 15;
    const int mb = blockIdx.y * 64, nb = blockIdx.x * 64;

    const int r = tid >> 2;
    const int c = (tid & 3) * 16;

    const size_t abase = (size_t)(mb + r) * CC + c;
    const size_t wbase = (size_t)(nb + r) * CC + c;

    f32x4 acc[4];
#pragma unroll
    for (int ct = 0; ct < 4; ct++) acc[ct] = (f32x4){0.f, 0.f, 0.f, 0.f};

    uint4 a0, a1, w0, w1;
    ld16(A, abase, aFl, a0, a1);
    ld16(W, wbase, wFl, w0, w1);

#pragma unroll
    for (int step = 0; step < 8; step++) {
        *(uint4*)&As[r][c] = a0; *(uint4*)&As[r][c + 8] = a1;
        *(uint4*)&Ws[r][c] = w0; *(uint4*)&Ws[r][c + 8] = w1;
        __syncthreads();
        if (step < 7) {
            const int kb = (step + 1) * 64;
            ld16(A, abase + kb, aFl, a0, a1);
            ld16(W, wbase + kb, wFl, w0, w1);
        }
#pragma unroll
        for (int kk = 0; kk < 2; kk++) {
            FragU af; af.u = *(const uint4*)&As[w * 16 + li][kk * 32 + quad * 8];
#pragma unroll
            for (int ct = 0; ct < 4; ct++) {
                FragU wf; wf.u = *(const uint4*)&Ws[ct * 16 + li][kk * 32 + quad * 8];
                acc[ct] = __builtin_amdgcn_mfma_f32_16x16x32_bf16(af.b, wf.b, acc[ct], 0, 0, 0);
            }
        }
        __syncthreads();
    }

#pragma unroll
    for (int ct = 0; ct < 4; ct++) {
        const int n = nb + ct * 16 + li;
        const float bv = wFl ? bf2f(((const u16*)bias)[n]) : ((const float*)bias)[n];
#pragma unroll
        for (int rr = 0; rr < 4; rr++) {
            const int m = mb + w * 16 + quad * 4 + rr;
            const float v = acc[ct][rr] + bv;
            if (headperm) {
                const int b = (m >= TT) ? 1 : 0;
                const int tloc = m - b * TT;
                ((u16*)out)[((size_t)(b * HH + (n >> 6)) * TT + tloc) * DD + (n & 63)] = f2bf(v);
            } else {
                if (outFl) ((u16*)out)[(size_t)m * CC + n] = f2bf(v);
                else       ((float*)out)[(size_t)m * CC + n] = v;
            }
        }
    }
}

__global__ __launch_bounds__(256) void proj5_kernel(
    const void* __restrict__ x,
    const void* __restrict__ Wq,  const void* __restrict__ bq,
    const void* __restrict__ Wk0, const void* __restrict__ bk0,
    const void* __restrict__ Wk1, const void* __restrict__ bk1,
    const void* __restrict__ Wv0, const void* __restrict__ bv0,
    const void* __restrict__ Wv1, const void* __restrict__ bv1,
    u16* __restrict__ ws16) {
    const u32 fl = detect_bf16_fast((const u32*)x);
    const int z = blockIdx.z;
    const void* W; const void* bi;
    switch (z) {
        case 0:  W = Wq;  bi = bq;  break;
        case 1:  W = Wk0; bi = bk0; break;
        case 2:  W = Wk1; bi = bk1; break;
        case 3:  W = Wv0; bi = bv0; break;
        default: W = Wv1; bi = bv1; break;
    }
    proj_lds(x, fl, W, bi, fl, (void*)(ws16 + (size_t)z * TSZ), 1, 1u);
}

__global__ __launch_bounds__(256) void projo_kernel(const u16* __restrict__ ws16,
                                                    const void* __restrict__ Wo,
                                                    const void* __restrict__ bo,
                                                    void* __restrict__ out,
                                                    const void* __restrict__ xorig) {
    const u32 fl = detect_bf16_fast((const u32*)xorig);
    proj_lds(ws16 + OFF_ATT, 1u, Wo, bo, fl, out, 0, fl);
}

// ---------------------------------------------------------------------------
// MFMA attention (r9-verified core; r11-verified 4-k grouping).
// Block = (b,h, kgroup of 4), 4 waves; wave owns 48 l-rows.
// v1^T staged ONCE per 4 k's (amortizes staging DS+VMEM 4x).
// GEMM1 (transposed): S^T[m,l] = sum_d k1[m,d]*(scl*q[d]*k0[l,d]),
//   k1-frags b128 from global. v_exp_f32 -> P bf16 (trunc pack) -> b64 write.
// GEMM2: W'[l,d] += P[l,m]*v1[m,d]; Z[l] via mfma(P, ones).
// epilogue: out[d] = sum_l v0[l,d] * W'[l,d] * rcp(Z[l]), v0 from global.
// LDS 40960B: v1t [64 d][200] swz @0 | P [192 l][40] @12800 (osum overlays).
// NOTE: no min-waves bound (r5: spills); no m-unroll (r7); v1t stays in LDS
// (r8: natural-layout global B-frags = 64-line splits, regressed).
// ---------------------------------------------------------------------------
#define LP_P  12800
#define LP_OS 12800

__global__ __launch_bounds__(256) void attn_kernel(u16* __restrict__ ws16) {
    __shared__ __align__(16) u16 smem[20480];   // 40960 B
    const int tid = threadIdx.x;
    const int w = tid >> 6, lane = tid & 63;
    const int quad = lane >> 4, li = lane & 15;
    const int kbase = blockIdx.x * 4, bh = blockIdx.y;

    const u16* k0g = ws16 + TSZ     + (size_t)bh * TT * DD;
    const u16* k1g = ws16 + 2 * TSZ + (size_t)bh * TT * DD;
    const u16* v0g = ws16 + 3 * TSZ + (size_t)bh * TT * DD;
    const u16* v1g = ws16 + 4 * TSZ + (size_t)bh * TT * DD;

    // ---- stage v1^T once (stride 200, swz (m>>3)^(d>>3); stores 2-way max) ----
#pragma unroll
    for (int it = 0; it < 6; it++) {
        const int flat = (it * 256 + tid) * 8;
        const int row = flat >> 6, c0 = flat & 63;   // row=m, c0=d base
        uint4 b = *(const uint4*)(v1g + flat);
        u16 vb[8]; *(uint4*)vb = b;
        const int swz = (((row >> 3) ^ (c0 >> 3)) << 3) | (row & 7);
#pragma unroll
        for (int j = 0; j < 8; j++)
            smem[(c0 + j) * 200 + swz] = vb[j];
    }
    __syncthreads();   // v1t staged

    FragU ones;
    ones.u = make_uint4(0x3F803F80u, 0x3F803F80u, 0x3F803F80u, 0x3F803F80u);

    for (int ki = 0; ki < 4; ki++) {
        const int k = kbase + ki;
        const u16* qg = ws16 + ((size_t)bh * TT + k) * DD;

        // ---- afr: a[l,d] = bf16_trunc(scl*q[d]*k0[l,d]), scl=0.125*log2e ----
        FragU afr[3][2];
#pragma unroll
        for (int kk = 0; kk < 2; kk++) {
            uint4 qu = *(const uint4*)(qg + kk * 32 + quad * 8);
            u16 qv[8]; *(uint4*)qv = qu;
            float qf[8];
#pragma unroll
            for (int j = 0; j < 8; j++) qf[j] = bf2f(qv[j]) * 0.18033688f;
#pragma unroll
            for (int rt = 0; rt < 3; rt++) {
                uint4 ku = *(const uint4*)(k0g + (size_t)(w * 48 + rt * 16 + li) * DD + kk * 32 + quad * 8);
                u16 kv[8]; *(uint4*)kv = ku;
                u32 pk[4];
#pragma unroll
                for (int p = 0; p < 4; p++) {
                    u32 lo = __float_as_uint(qf[2 * p] * bf2f(kv[2 * p]));
                    u32 hi = __float_as_uint(qf[2 * p + 1] * bf2f(kv[2 * p + 1]));
                    pk[p] = trunc_pk(hi, lo);
                }
                afr[rt][kk].u = make_uint4(pk[0], pk[1], pk[2], pk[3]);
            }
        }

        f32x4 Wacc[3][4], Zacc[3];
#pragma unroll
        for (int rt = 0; rt < 3; rt++) {
            Zacc[rt] = (f32x4){0.f, 0.f, 0.f, 0.f};
#pragma unroll
            for (int cd = 0; cd < 4; cd++) Wacc[rt][cd] = (f32x4){0.f, 0.f, 0.f, 0.f};
        }

        // ---- m-tile loop (6 x 32), barrier-free (P rows wave-private) ----
        for (int mt = 0; mt < 6; mt++) {
#pragma unroll
            for (int ct = 0; ct < 2; ct++) {
                const u16* krow = k1g + (size_t)(mt * 32 + ct * 16 + li) * DD + quad * 8;
                FragU kf0, kf1;
                kf0.u = *(const uint4*)(krow);
                kf1.u = *(const uint4*)(krow + 32);
#pragma unroll
                for (int rt = 0; rt < 3; rt++) {
                    f32x4 acc = (f32x4){0.f, 0.f, 0.f, 0.f};
                    acc = __builtin_amdgcn_mfma_f32_16x16x32_bf16(kf0.b, afr[rt][0].b, acc, 0, 0, 0);
                    acc = __builtin_amdgcn_mfma_f32_16x16x32_bf16(kf1.b, afr[rt][1].b, acc, 0, 0, 0);
                    u32 lo = trunc_pk(__float_as_uint(EXP2F(acc[1])), __float_as_uint(EXP2F(acc[0])));
                    u32 hi = trunc_pk(__float_as_uint(EXP2F(acc[3])), __float_as_uint(EXP2F(acc[2])));
                    const int l = w * 48 + rt * 16 + li;
                    *(uint2*)(smem + LP_P + l * 40 + ct * 16 + quad * 4) = make_uint2(lo, hi);
                }
            }
            FragU a2[3], b2[4];
#pragma unroll
            for (int rt = 0; rt < 3; rt++)
                a2[rt].u = *(const uint4*)(smem + LP_P + (w * 48 + rt * 16 + li) * 40 + quad * 8);
#pragma unroll
            for (int cd = 0; cd < 4; cd++) {
                const int d = cd * 16 + li;
                b2[cd].u = *(const uint4*)(smem + d * 200 + (((mt * 4 + quad) ^ (d >> 3)) << 3));
            }
#pragma unroll
            for (int rt = 0; rt < 3; rt++) {
                Zacc[rt] = __builtin_amdgcn_mfma_f32_16x16x32_bf16(a2[rt].b, ones.b, Zacc[rt], 0, 0, 0);
#pragma unroll
                for (int cd = 0; cd < 4; cd++)
                    Wacc[rt][cd] = __builtin_amdgcn_mfma_f32_16x16x32_bf16(a2[rt].b, b2[cd].b, Wacc[rt][cd], 0, 0, 0);
            }
        }

        __syncthreads();   // all waves done with this k's P (osum overlays P rows 0..12)

        // ---- epilogue: v0 from global, per-rt to cap live VGPRs ----
        float op[4] = {0.f, 0.f, 0.f, 0.f};
#pragma unroll
        for (int rt = 0; rt < 3; rt++) {
            float v0v[4][4];
#pragma unroll
            for (int r = 0; r < 4; r++) {
                const int l = w * 48 + rt * 16 + quad * 4 + r;
#pragma unroll
                for (int cd = 0; cd < 4; cd++)
                    v0v[r][cd] = bf2f(v0g[(size_t)l * DD + cd * 16 + li]);
            }
#pragma unroll
            for (int r = 0; r < 4; r++) {
                const float iv = RCPF(Zacc[rt][r]);
#pragma unroll
                for (int cd = 0; cd < 4; cd++)
                    op[cd] = fmaf(v0v[r][cd] * iv, Wacc[rt][cd][r], op[cd]);
            }
        }
#pragma unroll
        for (int cd = 0; cd < 4; cd++) {
            op[cd] += __shfl_xor(op[cd], 16);
            op[cd] += __shfl_xor(op[cd], 32);
        }
        float* osum = (float*)(smem + LP_OS);
        if (quad == 0) {
#pragma unroll
            for (int cd = 0; cd < 4; cd++) osum[w * 64 + cd * 16 + li] = op[cd];
        }
        __syncthreads();
        if (tid < DD) {
            const float o = osum[tid] + osum[64 + tid] + osum[128 + tid] + osum[192 + tid];
            const int b = bh >> 3, h = bh & 7;
            u16* ATT = ws16 + OFF_ATT;
            ATT[((size_t)(b * TT + k)) * CC + h * DD + tid] = f2bf(o);
        }
        // Race audit (verified r11 run): osum readers = wave 0; the only
        // next-iteration P writes overlapping osum are wave 0's own rows
        // (same-wave program order); v1t region [0,12800) disjoint. Safe.
    }
}

extern "C" void kernel_launch(void* const* d_in, const int* in_sizes, int n_in,
                              void* d_out, int out_size, void* d_ws, size_t ws_size,
                              hipStream_t stream) {
    u16* ws16 = (u16*)d_ws;

    dim3 gp(CC / 64, MM / 64, 5);   // 8 x 6 x 5
    proj5_kernel<<<gp, 256, 0, stream>>>(
        d_in[0], d_in[1], d_in[2], d_in[3], d_in[4], d_in[5], d_in[6],
        d_in[7], d_in[8], d_in[9], d_in[10], ws16);

    dim3 ga(TT / 4, BB * HH);       // 48 x 16, 4 k's per block
    attn_kernel<<<ga, 256, 0, stream>>>(ws16);

    dim3 go(CC / 64, MM / 64, 1);   // 8 x 6
    projo_kernel<<<go, 256, 0, stream>>>(ws16, d_in[11], d_in[12], d_out, d_in[0]);
}

// Round 14
// 153.652 us; speedup vs baseline: 1.6195x; 1.1341x over previous
//
#include <hip/hip_runtime.h>
#include <hip/hip_bf16.h>

typedef unsigned short u16;
typedef unsigned int u32;

#define TT 192
#define BB 2
#define HH 8
#define DD 64
#define CC 512
#define MM (BB*TT)   // 384

// ws layout (u16 elements): Q,K0,K1,V0,V1 each [bh][t][d], then ATT [m][c]
#define TSZ   ((size_t)MM * CC)
#define OFF_ATT (5 * TSZ)

typedef short bf16x8 __attribute__((ext_vector_type(8)));
typedef float f32x4  __attribute__((ext_vector_type(4)));

union FragU { uint4 u; bf16x8 b; };

// Raw HW transcendentals (r13-verified: VALUBusy 58->27%): one v_exp_f32 /
// v_rcp_f32 instead of guarded libm sequences. ~1ulp, irrelevant vs 2% tol.
#if __has_builtin(__builtin_amdgcn_exp2f)
#define EXP2F(x) __builtin_amdgcn_exp2f(x)
#else
#define EXP2F(x) exp2f(x)
#endif
#if __has_builtin(__builtin_amdgcn_rcpf)
#define RCPF(x) __builtin_amdgcn_rcpf(x)
#else
#define RCPF(x) (1.f / (x))
#endif

__device__ __forceinline__ float bf2f(u16 u) {
    return __uint_as_float(((u32)u) << 16);
}
__device__ __forceinline__ u16 f2bf(float f) {
    u32 u = __float_as_uint(f);
    u32 r = u + 0x7FFFu + ((u >> 16) & 1u);   // RNE
    return (u16)(r >> 16);
}
// pack hi16(a),hi16(b) -> one u32 (truncation round; bias cancels in P/Z)
__device__ __forceinline__ u32 trunc_pk(u32 b_hi, u32 a_lo) {
    return __builtin_amdgcn_perm(b_hi, a_lo, 0x07060302u);
}

// dtype detect: 1 load + ballot. bf16 data => low u16 exponent near 127.
__device__ __forceinline__ u32 detect_bf16_fast(const u32* __restrict__ x) {
    const int lane = threadIdx.x & 63;
    u32 v = x[lane & 31];
    u32 e = (v >> 7) & 0xFF;
    unsigned long long m = __ballot(e >= 113 && e <= 133);
    return (__popcll(m) >= 32) ? 1u : 0u;
}

// dtype-aware 16-element load (two uint4 of packed bf16)
__device__ __forceinline__ void ld16(const void* __restrict__ base, size_t off, u32 fl,
                                     uint4& lo, uint4& hi) {
    if (fl) {
        const uint4* p = (const uint4*)((const u16*)base + off);
        lo = p[0]; hi = p[1];
    } else {
        const float* s = (const float*)base + off;
        float4 f0 = *(const float4*)(s);
        float4 f1 = *(const float4*)(s + 4);
        float4 f2 = *(const float4*)(s + 8);
        float4 f3 = *(const float4*)(s + 12);
        lo = make_uint4((u32)f2bf(f0.x) | ((u32)f2bf(f0.y) << 16),
                        (u32)f2bf(f0.z) | ((u32)f2bf(f0.w) << 16),
                        (u32)f2bf(f1.x) | ((u32)f2bf(f1.y) << 16),
                        (u32)f2bf(f1.z) | ((u32)f2bf(f1.w) << 16));
        hi = make_uint4((u32)f2bf(f2.x) | ((u32)f2bf(f2.y) << 16),
                        (u32)f2bf(f2.z) | ((u32)f2bf(f2.w) << 16),
                        (u32)f2bf(f3.x) | ((u32)f2bf(f3.y) << 16),
                        (u32)f2bf(f3.z) | ((u32)f2bf(f3.w) << 16));
    }
}

// ---------------------------------------------------------------------------
// LDS-staged MFMA projection GEMM (r9-verified): out = A @ W^T + bias.
// 64x64 tile, 4 waves, BK=64, coalesced 128B staging, stride-72 LDS,
// register prefetch of step k+1.
// ---------------------------------------------------------------------------
__device__ __forceinline__ void proj_lds(const void* __restrict__ A, u32 aFl,
                                         const void* __restrict__ W,
                                         const void* __restrict__ bias, u32 wFl,
                                         void* __restrict__ out, int headperm, u32 outFl) {
    __shared__ __align__(16) u16 As[64][72];
    __shared__ __align__(16) u16 Ws[64][72];
    const int tid = threadIdx.x;
    const int w = tid >> 6, lane = tid & 63;
    const int quad = lane >> 4, li = lane & 15;
    const int mb = blockIdx.y * 64, nb = blockIdx.x * 64;

    const int r = tid >> 2;
    const int c = (tid & 3) * 16;

    const size_t abase = (size_t)(mb + r) * CC + c;
    const size_t wbase = (size_t)(nb + r) * CC + c;

    f32x4 acc[4];
#pragma unroll
    for (int ct = 0; ct < 4; ct++) acc[ct] = (f32x4){0.f, 0.f, 0.f, 0.f};

    uint4 a0, a1, w0, w1;
    ld16(A, abase, aFl, a0, a1);
    ld16(W, wbase, wFl, w0, w1);

#pragma unroll
    for (int step = 0; step < 8; step++) {
        *(uint4*)&As[r][c] = a0; *(uint4*)&As[r][c + 8] = a1;
        *(uint4*)&Ws[r][c] = w0; *(uint4*)&Ws[r][c + 8] = w1;
        __syncthreads();
        if (step < 7) {
            const int kb = (step + 1) * 64;
            ld16(A, abase + kb, aFl, a0, a1);
            ld16(W, wbase + kb, wFl, w0, w1);
        }
#pragma unroll
        for (int kk = 0; kk < 2; kk++) {
            FragU af; af.u = *(const uint4*)&As[w * 16 + li][kk * 32 + quad * 8];
#pragma unroll
            for (int ct = 0; ct < 4; ct++) {
                FragU wf; wf.u = *(const uint4*)&Ws[ct * 16 + li][kk * 32 + quad * 8];
                acc[ct] = __builtin_amdgcn_mfma_f32_16x16x32_bf16(af.b, wf.b, acc[ct], 0, 0, 0);
            }
        }
        __syncthreads();
    }

#pragma unroll
    for (int ct = 0; ct < 4; ct++) {
        const int n = nb + ct * 16 + li;
        const float bv = wFl ? bf2f(((const u16*)bias)[n]) : ((const float*)bias)[n];
#pragma unroll
        for (int rr = 0; rr < 4; rr++) {
            const int m = mb + w * 16 + quad * 4 + rr;
            const float v = acc[ct][rr] + bv;
            if (headperm) {
                const int b = (m >= TT) ? 1 : 0;
                const int tloc = m - b * TT;
                ((u16*)out)[((size_t)(b * HH + (n >> 6)) * TT + tloc) * DD + (n & 63)] = f2bf(v);
            } else {
                if (outFl) ((u16*)out)[(size_t)m * CC + n] = f2bf(v);
                else       ((float*)out)[(size_t)m * CC + n] = v;
            }
        }
    }
}

__global__ __launch_bounds__(256) void proj5_kernel(
    const void* __restrict__ x,
    const void* __restrict__ Wq,  const void* __restrict__ bq,
    const void* __restrict__ Wk0, const void* __restrict__ bk0,
    const void* __restrict__ Wk1, const void* __restrict__ bk1,
    const void* __restrict__ Wv0, const void* __restrict__ bv0,
    const void* __restrict__ Wv1, const void* __restrict__ bv1,
    u16* __restrict__ ws16) {
    const u32 fl = detect_bf16_fast((const u32*)x);
    const int z = blockIdx.z;
    const void* W; const void* bi;
    switch (z) {
        case 0:  W = Wq;  bi = bq;  break;
        case 1:  W = Wk0; bi = bk0; break;
        case 2:  W = Wk1; bi = bk1; break;
        case 3:  W = Wv0; bi = bv0; break;
        default: W = Wv1; bi = bv1; break;
    }
    proj_lds(x, fl, W, bi, fl, (void*)(ws16 + (size_t)z * TSZ), 1, 1u);
}

__global__ __launch_bounds__(256) void projo_kernel(const u16* __restrict__ ws16,
                                                    const void* __restrict__ Wo,
                                                    const void* __restrict__ bo,
                                                    void* __restrict__ out,
                                                    const void* __restrict__ xorig) {
    const u32 fl = detect_bf16_fast((const u32*)xorig);
    proj_lds(ws16 + OFF_ATT, 1u, Wo, bo, fl, out, 0, fl);
}

// ---------------------------------------------------------------------------
// MFMA attention = r9 structure (measured best: 72us, VGPR 88, 16 waves/CU)
// + r13's HW transcendentals (measured: halves VALUBusy).
// Block = (b,h,k) -- ONE k per block (r13's 4-k grouping pushed VGPR 88->132
// across the 128 occupancy cliff and regressed 72->81us; reverted).
// GEMM1 (transposed): S^T[m,l] = sum_d k1[m,d]*(scl*q[d]*k0[l,d]),
//   k1-frags b128 from global. v_exp_f32 -> P bf16 (trunc pack) -> b64 write.
// GEMM2: W'[l,d] += P[l,m]*v1[m,d] via v1^T staged swizzled in LDS;
//   Z[l] via mfma(P, ones).
// epilogue: out[d] = sum_l v0[l,d] * W'[l,d] * rcp(Z[l]), v0 from global.
// LDS 40960B: v1t [64 d][200] swz @0 | P [192 l][40] @12800 (osum overlays).
// NOTE: no min-waves bound (r5: spills); no m-unroll (r7); v1t in LDS (r8).
// ---------------------------------------------------------------------------
#define LP_P  12800
#define LP_OS 12800

__global__ __launch_bounds__(256) void attn_kernel(u16* __restrict__ ws16) {
    __shared__ __align__(16) u16 smem[20480];   // 40960 B
    const int tid = threadIdx.x;
    const int w = tid >> 6, lane = tid & 63;
    const int quad = lane >> 4, li = lane & 15;
    const int k = blockIdx.x, bh = blockIdx.y;

    const u16* qg  = ws16 + ((size_t)bh * TT + k) * DD;
    const u16* k0g = ws16 + TSZ     + (size_t)bh * TT * DD;
    const u16* k1g = ws16 + 2 * TSZ + (size_t)bh * TT * DD;
    const u16* v0g = ws16 + 3 * TSZ + (size_t)bh * TT * DD;
    const u16* v1g = ws16 + 4 * TSZ + (size_t)bh * TT * DD;

    // ---- stage v1^T (stride 200, swz (m>>3)^(d>>3); stores 2-way max) ----
#pragma unroll
    for (int it = 0; it < 6; it++) {
        const int flat = (it * 256 + tid) * 8;
        const int row = flat >> 6, c0 = flat & 63;   // row=m, c0=d base
        uint4 b = *(const uint4*)(v1g + flat);
        u16 vb[8]; *(uint4*)vb = b;
        const int swz = (((row >> 3) ^ (c0 >> 3)) << 3) | (row & 7);
#pragma unroll
        for (int j = 0; j < 8; j++)
            smem[(c0 + j) * 200 + swz] = vb[j];
    }

    // ---- afr: a[l,d] = bf16_trunc(scl*q[d]*k0[l,d]), scl=0.125*log2e ----
    FragU afr[3][2];
#pragma unroll
    for (int kk = 0; kk < 2; kk++) {
        uint4 qu = *(const uint4*)(qg + kk * 32 + quad * 8);
        u16 qv[8]; *(uint4*)qv = qu;
        float qf[8];
#pragma unroll
        for (int j = 0; j < 8; j++) qf[j] = bf2f(qv[j]) * 0.18033688f;
#pragma unroll
        for (int rt = 0; rt < 3; rt++) {
            uint4 ku = *(const uint4*)(k0g + (size_t)(w * 48 + rt * 16 + li) * DD + kk * 32 + quad * 8);
            u16 kv[8]; *(uint4*)kv = ku;
            u32 pk[4];
#pragma unroll
            for (int p = 0; p < 4; p++) {
                u32 lo = __float_as_uint(qf[2 * p] * bf2f(kv[2 * p]));
                u32 hi = __float_as_uint(qf[2 * p + 1] * bf2f(kv[2 * p + 1]));
                pk[p] = trunc_pk(hi, lo);
            }
            afr[rt][kk].u = make_uint4(pk[0], pk[1], pk[2], pk[3]);
        }
    }

    FragU ones;
    ones.u = make_uint4(0x3F803F80u, 0x3F803F80u, 0x3F803F80u, 0x3F803F80u);

    f32x4 Wacc[3][4], Zacc[3];
#pragma unroll
    for (int rt = 0; rt < 3; rt++) {
        Zacc[rt] = (f32x4){0.f, 0.f, 0.f, 0.f};
#pragma unroll
        for (int cd = 0; cd < 4; cd++) Wacc[rt][cd] = (f32x4){0.f, 0.f, 0.f, 0.f};
    }

    __syncthreads();   // v1t staged

    // ---- m-tile loop (6 x 32), barrier-free (P rows wave-private) ----
    for (int mt = 0; mt < 6; mt++) {
        // GEMM1 (transposed) + v_exp_f32 + truncation-packed b64 P-write
#pragma unroll
        for (int ct = 0; ct < 2; ct++) {
            const u16* krow = k1g + (size_t)(mt * 32 + ct * 16 + li) * DD + quad * 8;
            FragU kf0, kf1;
            kf0.u = *(const uint4*)(krow);
            kf1.u = *(const uint4*)(krow + 32);
#pragma unroll
            for (int rt = 0; rt < 3; rt++) {
                f32x4 acc = (f32x4){0.f, 0.f, 0.f, 0.f};
                acc = __builtin_amdgcn_mfma_f32_16x16x32_bf16(kf0.b, afr[rt][0].b, acc, 0, 0, 0);
                acc = __builtin_amdgcn_mfma_f32_16x16x32_bf16(kf1.b, afr[rt][1].b, acc, 0, 0, 0);
                u32 lo = trunc_pk(__float_as_uint(EXP2F(acc[1])), __float_as_uint(EXP2F(acc[0])));
                u32 hi = trunc_pk(__float_as_uint(EXP2F(acc[3])), __float_as_uint(EXP2F(acc[2])));
                const int l = w * 48 + rt * 16 + li;
                *(uint2*)(smem + LP_P + l * 40 + ct * 16 + quad * 4) = make_uint2(lo, hi);
            }
        }
        // GEMM2 + Z on MFMA pipe (B-frags b128 from swizzled v1t)
        FragU a2[3], b2[4];
#pragma unroll
        for (int rt = 0; rt < 3; rt++)
            a2[rt].u = *(const uint4*)(smem + LP_P + (w * 48 + rt * 16 + li) * 40 + quad * 8);
#pragma unroll
        for (int cd = 0; cd < 4; cd++) {
            const int d = cd * 16 + li;
            b2[cd].u = *(const uint4*)(smem + d * 200 + (((mt * 4 + quad) ^ (d >> 3)) << 3));
        }
#pragma unroll
        for (int rt = 0; rt < 3; rt++) {
            Zacc[rt] = __builtin_amdgcn_mfma_f32_16x16x32_bf16(a2[rt].b, ones.b, Zacc[rt], 0, 0, 0);
#pragma unroll
            for (int cd = 0; cd < 4; cd++)
                Wacc[rt][cd] = __builtin_amdgcn_mfma_f32_16x16x32_bf16(a2[rt].b, b2[cd].b, Wacc[rt][cd], 0, 0, 0);
        }
    }

    __syncthreads();   // all waves done with P/v1t (osum overlays P region)

    // ---- epilogue: v0 from global, per-rt to cap live VGPRs ----
    float op[4] = {0.f, 0.f, 0.f, 0.f};
#pragma unroll
    for (int rt = 0; rt < 3; rt++) {
        float v0v[4][4];
#pragma unroll
        for (int r = 0; r < 4; r++) {
            const int l = w * 48 + rt * 16 + quad * 4 + r;
#pragma unroll
            for (int cd = 0; cd < 4; cd++)
                v0v[r][cd] = bf2f(v0g[(size_t)l * DD + cd * 16 + li]);
        }
#pragma unroll
        for (int r = 0; r < 4; r++) {
            const float iv = RCPF(Zacc[rt][r]);
#pragma unroll
            for (int cd = 0; cd < 4; cd++)
                op[cd] = fmaf(v0v[r][cd] * iv, Wacc[rt][cd][r], op[cd]);
        }
    }
#pragma unroll
    for (int cd = 0; cd < 4; cd++) {
        op[cd] += __shfl_xor(op[cd], 16);
        op[cd] += __shfl_xor(op[cd], 32);
    }
    float* osum = (float*)(smem + LP_OS);
    if (quad == 0) {
#pragma unroll
        for (int cd = 0; cd < 4; cd++) osum[w * 64 + cd * 16 + li] = op[cd];
    }
    __syncthreads();
    if (tid < DD) {
        const float o = osum[tid] + osum[64 + tid] + osum[128 + tid] + osum[192 + tid];
        const int b = bh >> 3, h = bh & 7;
        u16* ATT = ws16 + OFF_ATT;
        ATT[((size_t)(b * TT + k)) * CC + h * DD + tid] = f2bf(o);
    }
}

extern "C" void kernel_launch(void* const* d_in, const int* in_sizes, int n_in,
                              void* d_out, int out_size, void* d_ws, size_t ws_size,
                              hipStream_t stream) {
    u16* ws16 = (u16*)d_ws;

    dim3 gp(CC / 64, MM / 64, 5);   // 8 x 6 x 5
    proj5_kernel<<<gp, 256, 0, stream>>>(
        d_in[0], d_in[1], d_in[2], d_in[3], d_in[4], d_in[5], d_in[6],
        d_in[7], d_in[8], d_in[9], d_in[10], ws16);

    dim3 ga(TT, BB * HH);           // 192 x 16, one k per block
    attn_kernel<<<ga, 256, 0, stream>>>(ws16);

    dim3 go(CC / 64, MM / 64, 1);   // 8 x 6
    projo_kernel<<<go, 256, 0, stream>>>(ws16, d_in[11], d_in[12], d_out, d_in[0]);
}